// Round 5
// baseline (851.293 us; speedup 1.0000x reference)
//
#include <hip/hip_runtime.h>

typedef unsigned int uint;
typedef unsigned short ushort;

#define TT 96
#define BB 128

// output element offsets (flat elements, return-order concatenation)
#define OFF_MUF   0          // mu_filt      [96,128,32,1]
#define OFF_SIGF  393216     // sigma_filt   [96,128,32,32]
#define OFF_MUP   12976128   // mu_pred      [96,128,32,1]
#define OFF_SIGP  13369344   // sigma_pred   [96,128,32,32]
#define OFF_LM    25952256   // latent_means [96,128,2,32,1]
#define OFF_LV    26738688   // latent_vars  [96,128,2,32,32]
#define OFF_ST    51904512   // S_tensor     [96,128,16,16]

__device__ __forceinline__ float bf2f(uint u) {
  union { uint i; float f; } c; c.i = u << 16; return c.f;
}
__device__ __forceinline__ float bflo(uint w) { return bf2f(w & 0xffffu); }
__device__ __forceinline__ float bfhi(uint w) { return bf2f(w >> 16); }

__device__ __forceinline__ ushort f2bf(float f) {   // RNE
  union { float f; uint i; } c; c.f = f;
  return (ushort)((c.i + 0x7fffu + ((c.i >> 16) & 1u)) >> 16);
}
__device__ __forceinline__ uint pack2(float a, float b) {
  return (uint)f2bf(a) | ((uint)f2bf(b) << 16);
}

// 3-way bf16 split: x ~= h + m + l with ~2^-25 relative error (fp32-equivalent)
__device__ __forceinline__ void split3(float x, ushort& h, ushort& m, ushort& l) {
  h = f2bf(x); float r = x - bf2f((uint)h);
  m = f2bf(r); r -= bf2f((uint)m);
  l = f2bf(r);
}

// uniform broadcast from a compile-time lane: pure VALU/SALU, no LDS.
__device__ __forceinline__ float readlane_f(float x, int l) {
  return __int_as_float(__builtin_amdgcn_readlane(__float_as_int(x), l));
}

// ---- dtype-generic load/store: F32=1 -> float32 buffers, F32=0 -> bf16 ----
template<int F32>
__device__ __forceinline__ float4 ld4(const void* p, long e) {
  if constexpr (F32) {
    return *(const float4*)((const float*)p + e);
  } else {
    uint2 w = *(const uint2*)((const ushort*)p + e);
    return make_float4(bflo(w.x), bfhi(w.x), bflo(w.y), bfhi(w.y));
  }
}
template<int F32>
__device__ __forceinline__ float ld1(const void* p, long e) {
  if constexpr (F32) return ((const float*)p)[e];
  else               return bf2f((uint)((const ushort*)p)[e]);
}
template<int F32>
__device__ __forceinline__ void st4(void* p, long e, float4 v) {
  if constexpr (F32) {
    *(float4*)((float*)p + e) = v;
  } else {
    uint2 w; w.x = pack2(v.x, v.y); w.y = pack2(v.z, v.w);
    *(uint2*)((ushort*)p + e) = w;
  }
}
template<int F32>
__device__ __forceinline__ void st1(void* p, long e, float v) {
  if constexpr (F32) ((float*)p)[e] = v;
  else               ((ushort*)p)[e] = f2bf(v);
}

// inline dtype detect via A[0,0,0,0,1] bit pattern (see earlier rounds)
__device__ __forceinline__ bool data_is_f32(const void* A) {
  ushort h = ((const ushort*)A)[1];
  return (h & 0x7FFF) >= 0x3E80;
}

// raw barrier: LDS-visibility only — does NOT drain vmcnt.
#define BAR() do { \
  __builtin_amdgcn_sched_barrier(0); \
  asm volatile("s_waitcnt lgkmcnt(0)" ::: "memory"); \
  __builtin_amdgcn_s_barrier(); \
  asm volatile("" ::: "memory"); \
  __builtin_amdgcn_sched_barrier(0); \
} while (0)

// ====================================================================
// VALU fallback (handles bf16 data; harness-verified structure).
// ====================================================================
template<int F32>
__global__ void __launch_bounds__(256)
hkv_kernel(const void* __restrict__ obs, const void* __restrict__ A,
           const void* __restrict__ C, const void* __restrict__ D,
           void* __restrict__ out)
{
  if (data_is_f32(A) != (F32 == 1)) return;
  const int tid = threadIdx.x;

  if (blockIdx.x >= BB) {
    const int fb = blockIdx.x - BB;
    const int NG = (TT * BB * 2 * 32 * 32) / 4;
    for (int g = fb * 256 + tid; g < NG; g += BB * 256) {
      int e0 = g << 2;
      int R  = e0 >> 5;
      int c0 = e0 & 31;
      int zi = R & 31;
      int l  = (R >> 5) & 1;
      int t  = R >> 13;
      float dv = 0.0f;
      if (l == 0) { if (t >= 2) dv = 0.08f; }
      else        { if (t < 4)  dv = 20.0f; }
      float4 w = make_float4(0.f, 0.f, 0.f, 0.f);
      if (dv != 0.0f && zi >= c0 && zi < c0 + 4) ((float*)&w)[zi - c0] = dv;
      st4<F32>(out, OFF_LV + (long)e0, w);
    }
    return;
  }

  const int b    = blockIdx.x;
  const int lane = tid & 63;
  const int wv   = tid >> 6;

  __shared__ __align__(16) float sig[32][36];
  __shared__ __align__(16) float an[32][36];
  __shared__ __align__(16) float ant[32][36];
  __shared__ __align__(16) float dnm[32][36];
  __shared__ __align__(16) float asig[32][36];
  __shared__ __align__(16) float asAt[32][36];
  __shared__ __align__(16) float ct[16][36];
  __shared__ __align__(16) float cts[16][36];
  __shared__ __align__(16) float Vm[16][36];
  __shared__ __align__(16) float Ks[32][20];
  __shared__ __align__(16) float Um[32][20];
  __shared__ __align__(16) float Ss[16][20];
  __shared__ __align__(16) float ch[24][32];
  __shared__ float muv[32], muz[32], rv[16], yv[16], ov[16];

  for (int idx = tid; idx < 1024; idx += 256) {
    int i = idx >> 5, j = idx & 31;
    sig[i][j] = (i == j) ? 20.0f : 0.0f;
  }
  if (tid < 32) muv[tid] = 0.0f;

  if (tid < 32) {
    const int zi = tid;
    float m = 0.01f;
    ch[0][zi] = m;
    float cur[32], nxt[32];
    {
      long base = (((long)b * TT + 4) * 3 + 2) * 1024 + zi * 32;
      #pragma unroll
      for (int u = 0; u < 8; ++u) {
        float4 v = ld4<F32>(A, base + u * 4);
        nxt[4*u] = v.x; nxt[4*u+1] = v.y; nxt[4*u+2] = v.z; nxt[4*u+3] = v.w;
      }
    }
    for (int j = 1; j < 24; ++j) {
      #pragma unroll
      for (int u = 0; u < 32; ++u) cur[u] = nxt[u];
      if (j < 23) {
        long base = (((long)b * TT + 4 * (j + 1)) * 3 + 2) * 1024 + zi * 32;
        #pragma unroll
        for (int u = 0; u < 8; ++u) {
          float4 v = ld4<F32>(A, base + u * 4);
          nxt[4*u] = v.x; nxt[4*u+1] = v.y; nxt[4*u+2] = v.z; nxt[4*u+3] = v.w;
        }
      }
      float mp = m;
      float s = 0.0f;
      #pragma unroll
      for (int k = 0; k < 32; ++k) s = fmaf(cur[k], __shfl(mp, k, 64), s);
      m = s;
      ch[j][zi] = m;
    }
  }
  __syncthreads();

  for (int t = 0; t < TT; ++t) {
    const long tb = (long)t * BB + b;

    {
      int e0 = tid << 2;
      int i = e0 >> 5, j0 = e0 & 31;
      st4<F32>(out, OFF_SIGP + tb * 1024 + e0,
               make_float4(sig[i][j0], sig[i][j0+1], sig[i][j0+2], sig[i][j0+3]));
    }
    if (t < TT - 1) {
      int e0 = tid << 2; int i = e0 >> 5, j = e0 & 31;
      float4 a4 = ld4<F32>(A, ((long)(b * TT + t + 1) * 3) * 1024 + e0);
      an[i][j] = a4.x; an[i][j+1] = a4.y; an[i][j+2] = a4.z; an[i][j+3] = a4.w;
      ant[j][i] = a4.x; ant[j+1][i] = a4.y; ant[j+2][i] = a4.z; ant[j+3][i] = a4.w;
      float4 d4 = ld4<F32>(D, ((long)(b * TT + t + 1) * 2) * 1024 + e0);
      dnm[i][j] = d4.x; dnm[i][j+1] = d4.y; dnm[i][j+2] = d4.z; dnm[i][j+3] = d4.w;
    } else {
      int e0 = tid << 2; int i = e0 >> 5, j = e0 & 31;
      #pragma unroll
      for (int u = 0; u < 4; ++u) {
        float v = (i == j + u) ? 1.0f : 0.0f;
        an[i][j + u] = v; ant[j + u][i] = v; dnm[i][j + u] = 0.0f;
      }
    }
    if (tid < 128) {
      int e0 = tid << 2; int i = e0 >> 5, j = e0 & 31;
      float4 c4 = ld4<F32>(C, ((long)b * TT + t) * 512 + e0);
      ct[i][j] = c4.x; ct[i][j+1] = c4.y; ct[i][j+2] = c4.z; ct[i][j+3] = c4.w;
    } else if (tid < 192) {
      int l = (tid - 128) >> 5, zi = tid & 31;
      st1<F32>(out, OFF_LM + (tb * 2 + l) * 32 + zi, l ? ch[t >> 2][zi] : 0.0f);
    } else if (tid < 224) {
      int i = tid - 192;
      st1<F32>(out, OFF_MUP + tb * 32 + i, muv[i]);
    } else if (tid < 240) {
      int i = tid - 224;
      ov[i] = ld1<F32>(obs, tb * 16 + i);
    }
    __syncthreads();

    if (tid < 128) {
      int i = tid >> 3, j0 = (tid & 7) << 2;
      float4 acc = make_float4(0.f, 0.f, 0.f, 0.f);
      for (int k = 0; k < 32; ++k) {
        float a = ct[i][k];
        float4 s4 = *(const float4*)&sig[k][j0];
        acc.x = fmaf(a, s4.x, acc.x); acc.y = fmaf(a, s4.y, acc.y);
        acc.z = fmaf(a, s4.z, acc.z); acc.w = fmaf(a, s4.w, acc.w);
      }
      *(float4*)&cts[i][j0] = acc;
    } else if (tid < 144) {
      int i = tid - 128;
      float s = ov[i];
      for (int k = 0; k < 32; ++k) s = fmaf(-ct[i][k], muv[k], s);
      rv[i] = s;
    }
    __syncthreads();

    {
      int i = tid >> 4, j = tid & 15;
      float s = (i == j) ? 0.03f : 0.0f;
      for (int k = 0; k < 32; k += 4) {
        float4 a4 = *(const float4*)&cts[i][k];
        float4 b4 = *(const float4*)&ct[j][k];
        s += a4.x * b4.x + a4.y * b4.y + a4.z * b4.z + a4.w * b4.w;
      }
      Ss[i][j] = s;
      st1<F32>(out, OFF_ST + tb * 256 + tid, s);
    }
    __syncthreads();

    if (wv == 0) {
      const int r = lane >> 2, q = lane & 3;
      float v[13];
      #pragma unroll
      for (int m = 0; m < 13; ++m) {
        int c = 4 * m + q;
        float x = 0.0f;
        if (c < 16) x = Ss[r][c];
        else if (c < 48) x = cts[r][c - 16];
        else if (c == 48) x = rv[r];
        v[m] = x;
      }
      #pragma unroll
      for (int p = 0; p < 16; ++p) {
        const int mp = p >> 2, qp = p & 3;
        float pv = __shfl(v[mp], 4 * p + qp, 64);
        float f  = __shfl(v[mp], 4 * r + qp, 64);
        float rc = 1.0f / pv;
        #pragma unroll
        for (int m = 0; m < 13; ++m) {
          float srow = __shfl(v[m], 4 * p + q, 64) * rc;
          v[m] = (r == p) ? srow : fmaf(-f, srow, v[m]);
        }
      }
      #pragma unroll
      for (int m = 0; m < 13; ++m) {
        int c = 4 * m + q;
        if (c >= 16 && c < 48) Ks[c - 16][r] = v[m];
        else if (c == 48) yv[r] = v[m];
      }
    } else {
      int tt = tid - 64;
      for (int idx = tt; idx < 256; idx += 192) {
        int i = idx >> 3, j0 = (idx & 7) << 2;
        float4 acc = make_float4(0.f, 0.f, 0.f, 0.f);
        for (int k = 0; k < 32; ++k) {
          float a = an[i][k];
          float4 s4 = *(const float4*)&sig[k][j0];
          acc.x = fmaf(a, s4.x, acc.x); acc.y = fmaf(a, s4.y, acc.y);
          acc.z = fmaf(a, s4.z, acc.z); acc.w = fmaf(a, s4.w, acc.w);
        }
        *(float4*)&asig[i][j0] = acc;
      }
      for (int idx = tt; idx < 512; idx += 192) {
        int i = idx >> 5, j = idx & 31;
        float s = 0.0f;
        for (int k = 0; k < 32; k += 4) {
          float4 c4 = *(const float4*)&cts[i][k];
          float4 a4 = *(const float4*)&an[j][k];
          s += c4.x * a4.x + c4.y * a4.y + c4.z * a4.z + c4.w * a4.w;
        }
        Vm[i][j] = s;
      }
    }
    __syncthreads();

    {
      int i = tid >> 3, j0 = (tid & 7) << 2;
      float4 acc = make_float4(0.f, 0.f, 0.f, 0.f);
      for (int k = 0; k < 32; ++k) {
        float a = asig[i][k];
        float4 s4 = *(const float4*)&ant[k][j0];
        acc.x = fmaf(a, s4.x, acc.x); acc.y = fmaf(a, s4.y, acc.y);
        acc.z = fmaf(a, s4.z, acc.z); acc.w = fmaf(a, s4.w, acc.w);
      }
      int dd = i - j0;
      if (dd == 0) acc.x += 0.08f; else if (dd == 1) acc.y += 0.08f;
      else if (dd == 2) acc.z += 0.08f; else if (dd == 3) acc.w += 0.08f;
      *(float4*)&asAt[i][j0] = acc;

      float4 sz = *(const float4*)&sig[i][j0];
      for (int k = 0; k < 16; ++k) {
        float a = Ks[i][k];
        float4 c4 = *(const float4*)&cts[k][j0];
        sz.x = fmaf(-a, c4.x, sz.x); sz.y = fmaf(-a, c4.y, sz.y);
        sz.z = fmaf(-a, c4.z, sz.z); sz.w = fmaf(-a, c4.w, sz.w);
      }
      st4<F32>(out, OFF_SIGF + tb * 1024 + (i * 32 + j0), sz);
    }
    if (tid < 128) {
      int i = tid >> 2, j0 = (tid & 3) << 2;
      float4 acc = make_float4(0.f, 0.f, 0.f, 0.f);
      for (int k = 0; k < 32; ++k) {
        float a = an[i][k];
        float4 k4 = *(const float4*)&Ks[k][j0];
        acc.x = fmaf(a, k4.x, acc.x); acc.y = fmaf(a, k4.y, acc.y);
        acc.z = fmaf(a, k4.z, acc.z); acc.w = fmaf(a, k4.w, acc.w);
      }
      *(float4*)&Um[i][j0] = acc;
    } else if (tid < 160) {
      int i = tid - 128;
      float s = muv[i];
      for (int k = 0; k < 16; ++k) s = fmaf(cts[k][i], yv[k], s);
      muz[i] = s;
      st1<F32>(out, OFF_MUF + tb * 32 + i, s);
    }
    __syncthreads();

    {
      int i = tid >> 3, j0 = (tid & 7) << 2;
      float4 acc = *(const float4*)&asAt[i][j0];
      for (int k = 0; k < 16; ++k) {
        float u = Um[i][k];
        float4 v4 = *(const float4*)&Vm[k][j0];
        acc.x = fmaf(-u, v4.x, acc.x); acc.y = fmaf(-u, v4.y, acc.y);
        acc.z = fmaf(-u, v4.z, acc.z); acc.w = fmaf(-u, v4.w, acc.w);
      }
      if (t < 4) {
        float4 da = make_float4(0.f, 0.f, 0.f, 0.f);
        for (int k = 0; k < 32; ++k) {
          float a = dnm[i][k];
          da.x = fmaf(a, dnm[j0][k],     da.x);
          da.y = fmaf(a, dnm[j0 + 1][k], da.y);
          da.z = fmaf(a, dnm[j0 + 2][k], da.z);
          da.w = fmaf(a, dnm[j0 + 3][k], da.w);
        }
        acc.x += 20.0f * da.x; acc.y += 20.0f * da.y;
        acc.z += 20.0f * da.z; acc.w += 20.0f * da.w;
      }
      *(float4*)&sig[i][j0] = acc;
    }
    if (tid < 32) {
      int i = tid;
      float s = 0.0f;
      for (int k = 0; k < 32; ++k) s = fmaf(an[i][k], muz[k], s);
      const float* chr = ch[t >> 2];
      for (int k = 0; k < 32; ++k) s = fmaf(dnm[i][k], chr[k], s);
      muv[i] = s;
    }
    __syncthreads();
  }
}

// ====================================================================
// fp32 path via MFMA, 3-way bf16 splits. This round:
//  - every intermediate computed in the TRANSPOSED orientation so its
//    C-layout (4 row-consecutive values/lane) maps to ONE packed 8-B
//    LDS write per plane (as_, w_, wt, aw, ks, u_, sg[symmetry]).
//  - GJ on [S | I | r] -> S^-1 (+y); K^T = S^-1*W^T and U^T = S^-1*AW^T
//    as parallel MFMA products (math-identical to An*K path).
//  - rv / mu_z / mu_next via register-resident fp32 inputs (no 3-plane
//    scalar LDS reads); mu_z via row-0 MFMA trick (W*y).
// ====================================================================
typedef __attribute__((ext_vector_type(8))) short bf16x8;
typedef __attribute__((ext_vector_type(4))) float f32x4;

#define MFMA16(a, b, c) __builtin_amdgcn_mfma_f32_16x16x32_bf16((a), (b), (c), 0, 0, 0)

__global__ void __launch_bounds__(256)
hkv_f32(const void* __restrict__ obs, const void* __restrict__ A,
        const void* __restrict__ C, const void* __restrict__ D,
        void* __restrict__ out)
{
  if (!data_is_f32(A)) return;
  const int tid = threadIdx.x;
  float* outf = (float*)out;

  if (blockIdx.x >= BB) {
    const int fb = blockIdx.x - BB;
    const int NG = (TT * BB * 2 * 32 * 32) / 4;
    for (int g = fb * 256 + tid; g < NG; g += BB * 256) {
      int e0 = g << 2;
      int R  = e0 >> 5;
      int c0 = e0 & 31;
      int zi = R & 31;
      int l  = (R >> 5) & 1;
      int t  = R >> 13;
      float dv = 0.0f;
      if (l == 0) { if (t >= 2) dv = 0.08f; }
      else        { if (t < 4)  dv = 20.0f; }
      float4 w = make_float4(0.f, 0.f, 0.f, 0.f);
      if (dv != 0.0f && zi >= c0 && zi < c0 + 4) ((float*)&w)[zi - c0] = dv;
      st4<1>(out, OFF_LV + (long)e0, w);
    }
    return;
  }

  const int b    = blockIdx.x;
  const int lane = tid & 63;
  const int wv   = tid >> 6;          // wave 0..3
  const int tm   = wv >> 1;           // quadrant row block
  const int tn   = wv & 1;            // quadrant col block
  const int lr   = lane & 15;
  const int lk   = lane >> 4;
  const int lk8  = lk << 3;
  const int lk4  = lk << 2;
  const int pi   = tid >> 3;          // input-slice row (0..31)
  const int pj   = (tid & 7) << 2;    // input-slice col base

  const float* Of = (const float*)obs;

  // 3-plane bf16 splits; strides 40/24 u16 (80/48 B, 8-B write aligned).
  __shared__ __align__(16) ushort sg[3][32][40];    // sigma (symmetric)
  __shared__ __align__(16) ushort an[3][32][40];    // A[:,t+1,0]
  __shared__ __align__(16) ushort dn[3][32][40];    // D[:,t+1,0]
  __shared__ __align__(16) ushort as_[3][32][40];   // asig = An*sigma (row-major)
  __shared__ __align__(16) ushort ct[3][16][40];    // C_t
  __shared__ __align__(16) ushort wt[3][16][40];    // W^T (row-major)
  __shared__ __align__(16) ushort sinv[3][16][40];  // S^-1 (symmetric)
  __shared__ __align__(16) ushort w_[3][32][24];    // W  (row-major)
  __shared__ __align__(16) ushort aw[3][32][24];    // AW (row-major)
  __shared__ __align__(16) ushort ks[3][32][24];    // K  (row-major)
  __shared__ __align__(16) ushort u_[3][32][24];    // U  (row-major)
  __shared__ __align__(16) float Ssf[16][20];
  __shared__ __align__(16) float ch[24][32];
  __shared__ __align__(16) float muv[32];
  __shared__ __align__(16) float muzv[32];
  __shared__ __align__(16) float rv[16];
  __shared__ __align__(16) float yv[16];
  __shared__ __align__(16) float ov[16];

  const bf16x8 z8 = {0, 0, 0, 0, 0, 0, 0, 0};
  #define FR40(P, rb) (*(const bf16x8*)&(P)[(rb) + lr][lk8])
  #define FR24(P, rb) ((lk < 2) ? (*(const bf16x8*)&(P)[(rb) + lr][lk8]) : z8)
  #define FRS(P)      ((lk < 2) ? (*(const bf16x8*)&(P)[lr][lk8]) : z8)
  // 6-term split product, 2 accumulator chains
  #define PROD6(acc, xh,xm,xl, yh,ym,yl) do { \
    f32x4 a1_ = {0.f,0.f,0.f,0.f}; \
    acc=MFMA16(xh,yh,acc); a1_=MFMA16(xm,yh,a1_); \
    acc=MFMA16(xh,ym,acc); a1_=MFMA16(xl,yh,a1_); \
    acc=MFMA16(xh,yl,acc); a1_=MFMA16(xm,ym,a1_); \
    acc += a1_; } while(0)
  // packed 3-plane write of 4 row-consecutive values (c0 % 4 == 0)
  #define PACKW(ARR, rr, c0, x0, x1, x2, x3) do { \
    ushort h0_,m0_,l0_,h1_,m1_,l1_,h2_,m2_,l2_,h3_,m3_,l3_; \
    split3((x0),h0_,m0_,l0_); split3((x1),h1_,m1_,l1_); \
    split3((x2),h2_,m2_,l2_); split3((x3),h3_,m3_,l3_); \
    *(uint2*)&ARR[0][rr][c0] = make_uint2((uint)h0_|((uint)h1_<<16),(uint)h2_|((uint)h3_<<16)); \
    *(uint2*)&ARR[1][rr][c0] = make_uint2((uint)m0_|((uint)m1_<<16),(uint)m2_|((uint)m3_<<16)); \
    *(uint2*)&ARR[2][rr][c0] = make_uint2((uint)l0_|((uint)l1_<<16),(uint)l2_|((uint)l3_<<16)); \
  } while(0)

  // ---------------- prologue ----------------
  float anc[4], dnc[4], ccur[4] = {0.f,0.f,0.f,0.f};
  {
    float4 a4 = ld4<1>(A, ((long)(b * TT + 1) * 3) * 1024 + (tid << 2));
    float4 d4 = ld4<1>(D, ((long)(b * TT + 1) * 2) * 1024 + (tid << 2));
    anc[0]=a4.x; anc[1]=a4.y; anc[2]=a4.z; anc[3]=a4.w;
    dnc[0]=d4.x; dnc[1]=d4.y; dnc[2]=d4.z; dnc[3]=d4.w;
    PACKW(an, pi, pj, anc[0], anc[1], anc[2], anc[3]);
    PACKW(dn, pi, pj, dnc[0], dnc[1], dnc[2], dnc[3]);
  }
  if (tid < 128) {
    float4 c4 = ld4<1>(C, ((long)b * TT) * 512 + (tid << 2));
    ccur[0]=c4.x; ccur[1]=c4.y; ccur[2]=c4.z; ccur[3]=c4.w;
    PACKW(ct, (tid >> 3), ((tid & 7) << 2), ccur[0], ccur[1], ccur[2], ccur[3]);
  } else if (tid < 144) {
    ov[tid - 128] = Of[(long)b * 16 + (tid - 128)];
  }
  for (int idx = tid; idx < 1024; idx += 256) {
    int i = idx >> 5, j = idx & 31;
    sg[0][i][j] = (i == j) ? 0x41A0 : 0;   // bf16(20.0), exact
    sg[1][i][j] = 0; sg[2][i][j] = 0;
  }
  if (tid < 32) muv[tid] = 0.0f;

  float sig_reg[4];                          // fp32 sigma quadrant elements
  #pragma unroll
  for (int v = 0; v < 4; ++v) {
    int rr = 16 * tm + lk4 + v, cc = 16 * tn + lr;
    sig_reg[v] = (rr == cc) ? 20.0f : 0.0f;
  }

  if (tid < 32) {   // level-1 jump-mean chain (fp32, unchanged)
    const int zi = tid;
    float m = 0.01f;
    ch[0][zi] = m;
    float curv[32], nxtv[32];
    {
      long base = (((long)b * TT + 4) * 3 + 2) * 1024 + zi * 32;
      #pragma unroll
      for (int u = 0; u < 8; ++u) {
        float4 v = ld4<1>(A, base + u * 4);
        nxtv[4*u]=v.x; nxtv[4*u+1]=v.y; nxtv[4*u+2]=v.z; nxtv[4*u+3]=v.w;
      }
    }
    for (int j = 1; j < 24; ++j) {
      #pragma unroll
      for (int u = 0; u < 32; ++u) curv[u] = nxtv[u];
      if (j < 23) {
        long base = (((long)b * TT + 4 * (j + 1)) * 3 + 2) * 1024 + zi * 32;
        #pragma unroll
        for (int u = 0; u < 8; ++u) {
          float4 v = ld4<1>(A, base + u * 4);
          nxtv[4*u]=v.x; nxtv[4*u+1]=v.y; nxtv[4*u+2]=v.z; nxtv[4*u+3]=v.w;
        }
      }
      float mp = m, s = 0.0f;
      #pragma unroll
      for (int k = 0; k < 32; ++k) s = fmaf(curv[k], __shfl(mp, k, 64), s);
      m = s;
      ch[j][zi] = m;
    }
  }
  BAR();

  for (int t = 0; t < TT; ++t) {
    const long tb = (long)t * BB + b;

    // ===== P1: asig^T-product (all, packed as_); W^T-product (w0/w1 -> w_);
    //           W-product (w2/w3 -> wt); rv (w0/w1); LM+MUP (w3) =====
    {
      // P = sigma * An^T = asig^T ; quadrant rows 16tm, cols 16tn
      bf16x8 xh = FR40(sg[0], 16*tm), xm = FR40(sg[1], 16*tm), xl = FR40(sg[2], 16*tm);
      bf16x8 yh = FR40(an[0], 16*tn), ym = FR40(an[1], 16*tn), yl = FR40(an[2], 16*tn);
      f32x4 pq = {0.f,0.f,0.f,0.f};
      PROD6(pq, xh,xm,xl, yh,ym,yl);
      #pragma unroll
      for (int v = 0; v < 4; ++v)
        outf[OFF_SIGP + tb * 1024 + (16*tm + lk4 + v) * 32 + (16*tn + lr)] = sig_reg[v];
      // as_[c][r..] = asig row-major, packed
      PACKW(as_, 16*tn + lr, 16*tm + lk4, pq[0], pq[1], pq[2], pq[3]);
    }
    if (wv < 2) {
      // W^T-product: P = C * sigma = W^T ; col-block J=wv -> w_ packed
      const int J = wv;
      bf16x8 xh = FR40(ct[0], 0), xm = FR40(ct[1], 0), xl = FR40(ct[2], 0);
      bf16x8 yh = FR40(sg[0], 16*J), ym = FR40(sg[1], 16*J), yl = FR40(sg[2], 16*J);
      f32x4 q = {0.f,0.f,0.f,0.f};
      PROD6(q, xh,xm,xl, yh,ym,yl);
      PACKW(w_, 16*J + lr, lk4, q[0], q[1], q[2], q[3]);
      // rv: tid<128 threads hold ccur = C[pi][pj..pj+3]
      float4 m4 = *(const float4*)&muv[pj];
      float part = ccur[0]*m4.x;
      part = fmaf(ccur[1], m4.y, part);
      part = fmaf(ccur[2], m4.z, part);
      part = fmaf(ccur[3], m4.w, part);
      part += __shfl_xor(part, 1, 64);
      part += __shfl_xor(part, 2, 64);
      part += __shfl_xor(part, 4, 64);
      if ((tid & 7) == 0) rv[pi] = ov[pi] - part;
    } else {
      // W-product: P = sigma * C^T = W ; row-block a -> wt packed
      const int a = wv - 2;
      bf16x8 xh = FR40(sg[0], 16*a), xm = FR40(sg[1], 16*a), xl = FR40(sg[2], 16*a);
      bf16x8 yh = FR40(ct[0], 0), ym = FR40(ct[1], 0), yl = FR40(ct[2], 0);
      f32x4 q = {0.f,0.f,0.f,0.f};
      PROD6(q, xh,xm,xl, yh,ym,yl);
      PACKW(wt, lr, 16*a + lk4, q[0], q[1], q[2], q[3]);
      if (wv == 3) {
        int l = lane >> 5, zi = lane & 31;
        outf[OFF_LM + (tb * 2 + l) * 32 + zi] = l ? ch[t >> 2][zi] : 0.0f;
        if (lane < 32) outf[OFF_MUP + tb * 32 + zi] = muv[zi];
      }
    }
    BAR();

    // ===== P2: prefetch-issue; asAt+Dterm (all, regs); S+GJ->S^-1,y (w0);
    //           AW^T (w1/w2 -> aw packed) =====
    float pa[4], pd[4], pc[4] = {0.f,0.f,0.f,0.f}; float pobs = 0.f;
    if (t < TT - 1) {
      if (t < TT - 2) {
        float4 a4 = ld4<1>(A, ((long)(b * TT + t + 2) * 3) * 1024 + (tid << 2));
        float4 d4 = ld4<1>(D, ((long)(b * TT + t + 2) * 2) * 1024 + (tid << 2));
        pa[0]=a4.x; pa[1]=a4.y; pa[2]=a4.z; pa[3]=a4.w;
        pd[0]=d4.x; pd[1]=d4.y; pd[2]=d4.z; pd[3]=d4.w;
      } else {
        #pragma unroll
        for (int u = 0; u < 4; ++u) { pa[u] = (pi == pj + u) ? 1.0f : 0.0f; pd[u] = 0.0f; }
      }
      if (tid < 128) {
        float4 c4 = ld4<1>(C, ((long)b * TT + (t + 1)) * 512 + (tid << 2));
        pc[0]=c4.x; pc[1]=c4.y; pc[2]=c4.z; pc[3]=c4.w;
      } else if (tid < 144) {
        pobs = Of[((long)(t + 1) * BB + b) * 16 + (tid - 128)];
      }
    }

    f32x4 acc_at = {0.f,0.f,0.f,0.f};
    {
      bf16x8 xh = FR40(as_[0], 16*tm), xm = FR40(as_[1], 16*tm), xl = FR40(as_[2], 16*tm);
      bf16x8 yh = FR40(an[0], 16*tn), ym = FR40(an[1], 16*tn), yl = FR40(an[2], 16*tn);
      PROD6(acc_at, xh,xm,xl, yh,ym,yl);     // asAt = asig * An^T
    }
    f32x4 acc_d = {0.f,0.f,0.f,0.f};
    if (t < 4) {
      bf16x8 xh = FR40(dn[0], 16*tm), xm = FR40(dn[1], 16*tm), xl = FR40(dn[2], 16*tm);
      bf16x8 yh = FR40(dn[0], 16*tn), ym = FR40(dn[1], 16*tn), yl = FR40(dn[2], 16*tn);
      PROD6(acc_d, xh,xm,xl, yh,ym,yl);      // Dn * Dn^T
    }

    if (wv == 0) {
      // S = C * W  (A = ct rows, B-array wt -> B = W)
      f32x4 s4 = {0.f,0.f,0.f,0.f};
      {
        bf16x8 xh = FR40(ct[0], 0), xm = FR40(ct[1], 0), xl = FR40(ct[2], 0);
        bf16x8 yh = FR40(wt[0], 0), ym = FR40(wt[1], 0), yl = FR40(wt[2], 0);
        PROD6(s4, xh,xm,xl, yh,ym,yl);
      }
      #pragma unroll
      for (int v = 0; v < 4; ++v) {
        int r = lk4 + v;
        float val = s4[v] + ((r == lr) ? 0.03f : 0.0f);
        Ssf[r][lr] = val;
        outf[OFF_ST + tb * 256 + r * 16 + lr] = val;
      }
      // ---- column-per-lane GJ on [S | I | r]: lanes 0..15 S, 16..31 I, 32 rhs
      const int c = lane;
      float gv[16];
      if (c < 16) {
        #pragma unroll
        for (int r = 0; r < 16; ++r) gv[r] = Ssf[r][c];
      } else if (c < 32) {
        #pragma unroll
        for (int r = 0; r < 16; ++r) gv[r] = (r == c - 16) ? 1.0f : 0.0f;
      } else if (c == 32) {
        #pragma unroll
        for (int r = 0; r < 16; ++r) gv[r] = rv[r];
      } else {
        #pragma unroll
        for (int r = 0; r < 16; ++r) gv[r] = 0.0f;
      }
      #pragma unroll
      for (int p = 0; p < 16; ++p) {
        float f[16];
        #pragma unroll
        for (int r = 0; r < 16; ++r) f[r] = readlane_f(gv[r], p);
        float rc = 1.0f / f[p];
        float srow = gv[p] * rc;
        #pragma unroll
        for (int r = 0; r < 16; ++r)
          if (r != p) gv[r] = fmaf(-f[r], srow, gv[r]);
        gv[p] = srow;
      }
      // writeback S^-1 (lanes 16..31 hold column j = row j by symmetry), packed
      if (c >= 16 && c < 32) {
        const int j = c - 16;
        #pragma unroll
        for (int u = 0; u < 4; ++u) {
          ushort h0,m0,l0,h1,m1,l1,h2,m2,l2,h3,m3,l3;
          split3(gv[4*u+0], h0,m0,l0); split3(gv[4*u+1], h1,m1,l1);
          split3(gv[4*u+2], h2,m2,l2); split3(gv[4*u+3], h3,m3,l3);
          *(uint2*)&sinv[0][j][4*u] = make_uint2((uint)h0|((uint)h1<<16),(uint)h2|((uint)h3<<16));
          *(uint2*)&sinv[1][j][4*u] = make_uint2((uint)m0|((uint)m1<<16),(uint)m2|((uint)m3<<16));
          *(uint2*)&sinv[2][j][4*u] = make_uint2((uint)l0|((uint)l1<<16),(uint)l2|((uint)l3<<16));
        }
      }
      // y = S^-1 r (lane 32) -> yv via readlane broadcast, single store
      float myy = 0.0f;
      #pragma unroll
      for (int r = 0; r < 16; ++r) {
        float s = readlane_f(gv[r], 32);
        if (lane == r) myy = s;
      }
      if (lane < 16) yv[lane] = myy;
    } else if (wv < 3) {
      // AW^T = W^T * An^T ; col-block J -> aw packed (aw = AW row-major)
      const int J = wv - 1;
      bf16x8 xh = FR40(wt[0], 0), xm = FR40(wt[1], 0), xl = FR40(wt[2], 0);
      bf16x8 yh = FR40(an[0], 16*J), ym = FR40(an[1], 16*J), yl = FR40(an[2], 16*J);
      f32x4 q = {0.f,0.f,0.f,0.f};
      PROD6(q, xh,xm,xl, yh,ym,yl);
      PACKW(aw, 16*J + lr, lk4, q[0], q[1], q[2], q[3]);
    }
    BAR();

    // ===== P3: K^T = S^-1*W^T (w0/w1 -> ks packed) + mu_z (MFMA row-0);
    //           U^T = S^-1*AW^T (w2/w3 -> u_ packed) =====
    if (wv < 2) {
      const int J = wv;
      bf16x8 sh = FRS(sinv[0]), sm = FRS(sinv[1]), sl = FRS(sinv[2]);
      bf16x8 wh = FR24(w_[0], 16*J), wm = FR24(w_[1], 16*J), wl = FR24(w_[2], 16*J);
      f32x4 kq = {0.f,0.f,0.f,0.f};
      PROD6(kq, sh,sm,sl, wh,wm,wl);          // K^T col-block J
      PACKW(ks, 16*J + lr, lk4, kq[0], kq[1], kq[2], kq[3]);
      // mu_z block J: row-0 MFMA with A row0 = y
      bf16x8 ayh = z8, aym = z8, ayl = z8;
      if (lr == 0 && lk < 2) {
        #pragma unroll
        for (int e = 0; e < 8; ++e) {
          ushort h_, m_, l_; split3(yv[lk8 + e], h_, m_, l_);
          ayh[e] = (short)h_; aym[e] = (short)m_; ayl[e] = (short)l_;
        }
      }
      f32x4 mq = {0.f,0.f,0.f,0.f};
      PROD6(mq, ayh,aym,ayl, wh,wm,wl);       // row0 = (W*y) block J
      if (lk == 0) {
        float m = muv[16*J + lr] + mq[0];
        muzv[16*J + lr] = m;
        outf[OFF_MUF + tb * 32 + 16*J + lr] = m;
      }
    } else {
      const int J = wv - 2;
      bf16x8 sh = FRS(sinv[0]), sm = FRS(sinv[1]), sl = FRS(sinv[2]);
      bf16x8 bh = FR24(aw[0], 16*J), bm = FR24(aw[1], 16*J), bl = FR24(aw[2], 16*J);
      f32x4 uq = {0.f,0.f,0.f,0.f};
      PROD6(uq, sh,sm,sl, bh,bm,bl);          // U^T col-block J
      PACKW(u_, 16*J + lr, lk4, uq[0], uq[1], uq[2], uq[3]);
    }
    BAR();

    // ===== P4: KW -> sigma_filt out; UW -> sigma'; mu_next; staging =====
    {
      bf16x8 xh = FR24(ks[0], 16*tm), xm = FR24(ks[1], 16*tm), xl = FR24(ks[2], 16*tm);
      bf16x8 yh = FR24(w_[0], 16*tn), ym = FR24(w_[1], 16*tn), yl = FR24(w_[2], 16*tn);
      f32x4 kw = {0.f,0.f,0.f,0.f};
      PROD6(kw, xh,xm,xl, yh,ym,yl);          // K * W^T quadrant
      #pragma unroll
      for (int v = 0; v < 4; ++v)
        outf[OFF_SIGF + tb * 1024 + (16*tm + lk4 + v) * 32 + (16*tn + lr)] = sig_reg[v] - kw[v];
    }
    {
      bf16x8 xh = FR24(u_[0], 16*tm), xm = FR24(u_[1], 16*tm), xl = FR24(u_[2], 16*tm);
      bf16x8 yh = FR24(aw[0], 16*tn), ym = FR24(aw[1], 16*tn), yl = FR24(aw[2], 16*tn);
      f32x4 uw = {0.f,0.f,0.f,0.f};
      PROD6(uw, xh,xm,xl, yh,ym,yl);          // U * AW^T quadrant
      float sp4[4];
      #pragma unroll
      for (int v = 0; v < 4; ++v) {
        int rr = 16*tm + lk4 + v, cc = 16*tn + lr;
        float sp = acc_at[v] - uw[v];
        if (rr == cc) sp += 0.08f;
        if (t < 4) sp = fmaf(20.0f, acc_d[v], sp);
        sig_reg[v] = sp;
        sp4[v] = sp;
      }
      // symmetric transposed packed write: sg[col][row..row+3]
      PACKW(sg, 16*tn + lr, 16*tm + lk4, sp4[0], sp4[1], sp4[2], sp4[3]);
    }
    {
      // mu_next[i] = An[i,:]*muz + Dn[i,:]*ch ; 8 threads/row, reg-resident A/D
      const float* chr = ch[t >> 2];
      float4 mz4 = *(const float4*)&muzv[pj];
      float4 ch4 = *(const float4*)&chr[pj];
      float part = anc[0]*mz4.x;
      part = fmaf(anc[1], mz4.y, part);
      part = fmaf(anc[2], mz4.z, part);
      part = fmaf(anc[3], mz4.w, part);
      part = fmaf(dnc[0], ch4.x, part);
      part = fmaf(dnc[1], ch4.y, part);
      part = fmaf(dnc[2], ch4.z, part);
      part = fmaf(dnc[3], ch4.w, part);
      part += __shfl_xor(part, 1, 64);
      part += __shfl_xor(part, 2, 64);
      part += __shfl_xor(part, 4, 64);
      if ((tid & 7) == 0) muv[pi] = part;
    }
    if (t < TT - 1) {
      PACKW(an, pi, pj, pa[0], pa[1], pa[2], pa[3]);
      PACKW(dn, pi, pj, pd[0], pd[1], pd[2], pd[3]);
      #pragma unroll
      for (int u = 0; u < 4; ++u) { anc[u] = pa[u]; dnc[u] = pd[u]; }
      if (tid < 128) {
        PACKW(ct, (tid >> 3), ((tid & 7) << 2), pc[0], pc[1], pc[2], pc[3]);
        #pragma unroll
        for (int u = 0; u < 4; ++u) ccur[u] = pc[u];
      } else if (tid < 144) {
        ov[tid - 128] = pobs;
      }
    }
    BAR();
  }
  #undef FR40
  #undef FR24
  #undef FRS
  #undef PROD6
  #undef PACKW
}

extern "C" void kernel_launch(void* const* d_in, const int* in_sizes, int n_in,
                              void* d_out, int out_size, void* d_ws, size_t ws_size,
                              hipStream_t stream) {
  const void* obs = d_in[0];
  const void* A   = d_in[1];
  const void* C   = d_in[2];
  const void* D   = d_in[3];
  (void)in_sizes; (void)n_in; (void)out_size; (void)d_ws; (void)ws_size;

  hkv_kernel<0><<<dim3(2 * BB), dim3(256), 0, stream>>>(obs, A, C, D, d_out);
  hkv_f32<<<dim3(2 * BB), dim3(256), 0, stream>>>(obs, A, C, D, d_out);
}

// Round 6
// 768.473 us; speedup vs baseline: 1.1078x; 1.1078x over previous
//
#include <hip/hip_runtime.h>

typedef unsigned int uint;
typedef unsigned short ushort;

#define TT 96
#define BB 128

// output element offsets (flat elements, return-order concatenation)
#define OFF_MUF   0          // mu_filt      [96,128,32,1]
#define OFF_SIGF  393216     // sigma_filt   [96,128,32,32]
#define OFF_MUP   12976128   // mu_pred      [96,128,32,1]
#define OFF_SIGP  13369344   // sigma_pred   [96,128,32,32]
#define OFF_LM    25952256   // latent_means [96,128,2,32,1]
#define OFF_LV    26738688   // latent_vars  [96,128,2,32,32]
#define OFF_ST    51904512   // S_tensor     [96,128,16,16]

__device__ __forceinline__ float bf2f(uint u) {
  union { uint i; float f; } c; c.i = u << 16; return c.f;
}
__device__ __forceinline__ float bflo(uint w) { return bf2f(w & 0xffffu); }
__device__ __forceinline__ float bfhi(uint w) { return bf2f(w >> 16); }

__device__ __forceinline__ ushort f2bf(float f) {   // RNE
  union { float f; uint i; } c; c.f = f;
  return (ushort)((c.i + 0x7fffu + ((c.i >> 16) & 1u)) >> 16);
}
__device__ __forceinline__ ushort f2bft(float f) {  // truncate (1 op)
  union { float f; uint i; } c; c.f = f;
  return (ushort)(c.i >> 16);
}
__device__ __forceinline__ uint pack2(float a, float b) {
  return (uint)f2bf(a) | ((uint)f2bf(b) << 16);
}

// 3-way bf16 split: trunc/trunc/RNE — x ~= h+m+l to ~2^-24 relative, cheap.
__device__ __forceinline__ void split3(float x, ushort& h, ushort& m, ushort& l) {
  h = f2bft(x); float r = x - bf2f((uint)h);
  m = f2bft(r); r -= bf2f((uint)m);
  l = f2bf(r);
}

// uniform broadcast from a compile-time lane: pure VALU/SALU, no LDS.
__device__ __forceinline__ float readlane_f(float x, int l) {
  return __int_as_float(__builtin_amdgcn_readlane(__float_as_int(x), l));
}

// DPP neighbor-add: ~2cy VALU, replaces ds_bpermute-based __shfl_xor (~120cy).
// CTRL: 0xB1 quad_perm[1,0,3,2] (xor1), 0x4E quad_perm[2,3,0,1] (xor2),
//       0x141 row_half_mirror (lane^7 within 8) — valid 3rd step for 8-lane sums.
template<int CTRL>
__device__ __forceinline__ float dpp_addf(float x) {
  int y = __builtin_amdgcn_update_dpp(0, __float_as_int(x), CTRL, 0xF, 0xF, true);
  return x + __int_as_float(y);
}

// ---- dtype-generic load/store: F32=1 -> float32 buffers, F32=0 -> bf16 ----
template<int F32>
__device__ __forceinline__ float4 ld4(const void* p, long e) {
  if constexpr (F32) {
    return *(const float4*)((const float*)p + e);
  } else {
    uint2 w = *(const uint2*)((const ushort*)p + e);
    return make_float4(bflo(w.x), bfhi(w.x), bflo(w.y), bfhi(w.y));
  }
}
template<int F32>
__device__ __forceinline__ float ld1(const void* p, long e) {
  if constexpr (F32) return ((const float*)p)[e];
  else               return bf2f((uint)((const ushort*)p)[e]);
}
template<int F32>
__device__ __forceinline__ void st4(void* p, long e, float4 v) {
  if constexpr (F32) {
    *(float4*)((float*)p + e) = v;
  } else {
    uint2 w; w.x = pack2(v.x, v.y); w.y = pack2(v.z, v.w);
    *(uint2*)((ushort*)p + e) = w;
  }
}
template<int F32>
__device__ __forceinline__ void st1(void* p, long e, float v) {
  if constexpr (F32) ((float*)p)[e] = v;
  else               ((ushort*)p)[e] = f2bf(v);
}

// inline dtype detect via A[0,0,0,0,1] bit pattern (see earlier rounds)
__device__ __forceinline__ bool data_is_f32(const void* A) {
  ushort h = ((const ushort*)A)[1];
  return (h & 0x7FFF) >= 0x3E80;
}

// raw barrier: LDS-visibility only — does NOT drain vmcnt.
#define BAR() do { \
  __builtin_amdgcn_sched_barrier(0); \
  asm volatile("s_waitcnt lgkmcnt(0)" ::: "memory"); \
  __builtin_amdgcn_s_barrier(); \
  asm volatile("" ::: "memory"); \
  __builtin_amdgcn_sched_barrier(0); \
} while (0)

// ====================================================================
// VALU fallback (handles bf16 data; harness-verified structure).
// ====================================================================
template<int F32>
__global__ void __launch_bounds__(256)
hkv_kernel(const void* __restrict__ obs, const void* __restrict__ A,
           const void* __restrict__ C, const void* __restrict__ D,
           void* __restrict__ out)
{
  if (data_is_f32(A) != (F32 == 1)) return;
  const int tid = threadIdx.x;

  if (blockIdx.x >= BB) {
    const int fb = blockIdx.x - BB;
    const int NG = (TT * BB * 2 * 32 * 32) / 4;
    for (int g = fb * 256 + tid; g < NG; g += BB * 256) {
      int e0 = g << 2;
      int R  = e0 >> 5;
      int c0 = e0 & 31;
      int zi = R & 31;
      int l  = (R >> 5) & 1;
      int t  = R >> 13;
      float dv = 0.0f;
      if (l == 0) { if (t >= 2) dv = 0.08f; }
      else        { if (t < 4)  dv = 20.0f; }
      float4 w = make_float4(0.f, 0.f, 0.f, 0.f);
      if (dv != 0.0f && zi >= c0 && zi < c0 + 4) ((float*)&w)[zi - c0] = dv;
      st4<F32>(out, OFF_LV + (long)e0, w);
    }
    return;
  }

  const int b    = blockIdx.x;
  const int lane = tid & 63;
  const int wv   = tid >> 6;

  __shared__ __align__(16) float sig[32][36];
  __shared__ __align__(16) float an[32][36];
  __shared__ __align__(16) float ant[32][36];
  __shared__ __align__(16) float dnm[32][36];
  __shared__ __align__(16) float asig[32][36];
  __shared__ __align__(16) float asAt[32][36];
  __shared__ __align__(16) float ct[16][36];
  __shared__ __align__(16) float cts[16][36];
  __shared__ __align__(16) float Vm[16][36];
  __shared__ __align__(16) float Ks[32][20];
  __shared__ __align__(16) float Um[32][20];
  __shared__ __align__(16) float Ss[16][20];
  __shared__ __align__(16) float ch[24][32];
  __shared__ float muv[32], muz[32], rv[16], yv[16], ov[16];

  for (int idx = tid; idx < 1024; idx += 256) {
    int i = idx >> 5, j = idx & 31;
    sig[i][j] = (i == j) ? 20.0f : 0.0f;
  }
  if (tid < 32) muv[tid] = 0.0f;

  if (tid < 32) {
    const int zi = tid;
    float m = 0.01f;
    ch[0][zi] = m;
    float cur[32], nxt[32];
    {
      long base = (((long)b * TT + 4) * 3 + 2) * 1024 + zi * 32;
      #pragma unroll
      for (int u = 0; u < 8; ++u) {
        float4 v = ld4<F32>(A, base + u * 4);
        nxt[4*u] = v.x; nxt[4*u+1] = v.y; nxt[4*u+2] = v.z; nxt[4*u+3] = v.w;
      }
    }
    for (int j = 1; j < 24; ++j) {
      #pragma unroll
      for (int u = 0; u < 32; ++u) cur[u] = nxt[u];
      if (j < 23) {
        long base = (((long)b * TT + 4 * (j + 1)) * 3 + 2) * 1024 + zi * 32;
        #pragma unroll
        for (int u = 0; u < 8; ++u) {
          float4 v = ld4<F32>(A, base + u * 4);
          nxt[4*u] = v.x; nxt[4*u+1] = v.y; nxt[4*u+2] = v.z; nxt[4*u+3] = v.w;
        }
      }
      float mp = m;
      float s = 0.0f;
      #pragma unroll
      for (int k = 0; k < 32; ++k) s = fmaf(cur[k], __shfl(mp, k, 64), s);
      m = s;
      ch[j][zi] = m;
    }
  }
  __syncthreads();

  for (int t = 0; t < TT; ++t) {
    const long tb = (long)t * BB + b;

    {
      int e0 = tid << 2;
      int i = e0 >> 5, j0 = e0 & 31;
      st4<F32>(out, OFF_SIGP + tb * 1024 + e0,
               make_float4(sig[i][j0], sig[i][j0+1], sig[i][j0+2], sig[i][j0+3]));
    }
    if (t < TT - 1) {
      int e0 = tid << 2; int i = e0 >> 5, j = e0 & 31;
      float4 a4 = ld4<F32>(A, ((long)(b * TT + t + 1) * 3) * 1024 + e0);
      an[i][j] = a4.x; an[i][j+1] = a4.y; an[i][j+2] = a4.z; an[i][j+3] = a4.w;
      ant[j][i] = a4.x; ant[j+1][i] = a4.y; ant[j+2][i] = a4.z; ant[j+3][i] = a4.w;
      float4 d4 = ld4<F32>(D, ((long)(b * TT + t + 1) * 2) * 1024 + e0);
      dnm[i][j] = d4.x; dnm[i][j+1] = d4.y; dnm[i][j+2] = d4.z; dnm[i][j+3] = d4.w;
    } else {
      int e0 = tid << 2; int i = e0 >> 5, j = e0 & 31;
      #pragma unroll
      for (int u = 0; u < 4; ++u) {
        float v = (i == j + u) ? 1.0f : 0.0f;
        an[i][j + u] = v; ant[j + u][i] = v; dnm[i][j + u] = 0.0f;
      }
    }
    if (tid < 128) {
      int e0 = tid << 2; int i = e0 >> 5, j = e0 & 31;
      float4 c4 = ld4<F32>(C, ((long)b * TT + t) * 512 + e0);
      ct[i][j] = c4.x; ct[i][j+1] = c4.y; ct[i][j+2] = c4.z; ct[i][j+3] = c4.w;
    } else if (tid < 192) {
      int l = (tid - 128) >> 5, zi = tid & 31;
      st1<F32>(out, OFF_LM + (tb * 2 + l) * 32 + zi, l ? ch[t >> 2][zi] : 0.0f);
    } else if (tid < 224) {
      int i = tid - 192;
      st1<F32>(out, OFF_MUP + tb * 32 + i, muv[i]);
    } else if (tid < 240) {
      int i = tid - 224;
      ov[i] = ld1<F32>(obs, tb * 16 + i);
    }
    __syncthreads();

    if (tid < 128) {
      int i = tid >> 3, j0 = (tid & 7) << 2;
      float4 acc = make_float4(0.f, 0.f, 0.f, 0.f);
      for (int k = 0; k < 32; ++k) {
        float a = ct[i][k];
        float4 s4 = *(const float4*)&sig[k][j0];
        acc.x = fmaf(a, s4.x, acc.x); acc.y = fmaf(a, s4.y, acc.y);
        acc.z = fmaf(a, s4.z, acc.z); acc.w = fmaf(a, s4.w, acc.w);
      }
      *(float4*)&cts[i][j0] = acc;
    } else if (tid < 144) {
      int i = tid - 128;
      float s = ov[i];
      for (int k = 0; k < 32; ++k) s = fmaf(-ct[i][k], muv[k], s);
      rv[i] = s;
    }
    __syncthreads();

    {
      int i = tid >> 4, j = tid & 15;
      float s = (i == j) ? 0.03f : 0.0f;
      for (int k = 0; k < 32; k += 4) {
        float4 a4 = *(const float4*)&cts[i][k];
        float4 b4 = *(const float4*)&ct[j][k];
        s += a4.x * b4.x + a4.y * b4.y + a4.z * b4.z + a4.w * b4.w;
      }
      Ss[i][j] = s;
      st1<F32>(out, OFF_ST + tb * 256 + tid, s);
    }
    __syncthreads();

    if (wv == 0) {
      const int r = lane >> 2, q = lane & 3;
      float v[13];
      #pragma unroll
      for (int m = 0; m < 13; ++m) {
        int c = 4 * m + q;
        float x = 0.0f;
        if (c < 16) x = Ss[r][c];
        else if (c < 48) x = cts[r][c - 16];
        else if (c == 48) x = rv[r];
        v[m] = x;
      }
      #pragma unroll
      for (int p = 0; p < 16; ++p) {
        const int mp = p >> 2, qp = p & 3;
        float pv = __shfl(v[mp], 4 * p + qp, 64);
        float f  = __shfl(v[mp], 4 * r + qp, 64);
        float rc = 1.0f / pv;
        #pragma unroll
        for (int m = 0; m < 13; ++m) {
          float srow = __shfl(v[m], 4 * p + q, 64) * rc;
          v[m] = (r == p) ? srow : fmaf(-f, srow, v[m]);
        }
      }
      #pragma unroll
      for (int m = 0; m < 13; ++m) {
        int c = 4 * m + q;
        if (c >= 16 && c < 48) Ks[c - 16][r] = v[m];
        else if (c == 48) yv[r] = v[m];
      }
    } else {
      int tt = tid - 64;
      for (int idx = tt; idx < 256; idx += 192) {
        int i = idx >> 3, j0 = (idx & 7) << 2;
        float4 acc = make_float4(0.f, 0.f, 0.f, 0.f);
        for (int k = 0; k < 32; ++k) {
          float a = an[i][k];
          float4 s4 = *(const float4*)&sig[k][j0];
          acc.x = fmaf(a, s4.x, acc.x); acc.y = fmaf(a, s4.y, acc.y);
          acc.z = fmaf(a, s4.z, acc.z); acc.w = fmaf(a, s4.w, acc.w);
        }
        *(float4*)&asig[i][j0] = acc;
      }
      for (int idx = tt; idx < 512; idx += 192) {
        int i = idx >> 5, j = idx & 31;
        float s = 0.0f;
        for (int k = 0; k < 32; k += 4) {
          float4 c4 = *(const float4*)&cts[i][k];
          float4 a4 = *(const float4*)&an[j][k];
          s += c4.x * a4.x + c4.y * a4.y + c4.z * a4.z + c4.w * a4.w;
        }
        Vm[i][j] = s;
      }
    }
    __syncthreads();

    {
      int i = tid >> 3, j0 = (tid & 7) << 2;
      float4 acc = make_float4(0.f, 0.f, 0.f, 0.f);
      for (int k = 0; k < 32; ++k) {
        float a = asig[i][k];
        float4 s4 = *(const float4*)&ant[k][j0];
        acc.x = fmaf(a, s4.x, acc.x); acc.y = fmaf(a, s4.y, acc.y);
        acc.z = fmaf(a, s4.z, acc.z); acc.w = fmaf(a, s4.w, acc.w);
      }
      int dd = i - j0;
      if (dd == 0) acc.x += 0.08f; else if (dd == 1) acc.y += 0.08f;
      else if (dd == 2) acc.z += 0.08f; else if (dd == 3) acc.w += 0.08f;
      *(float4*)&asAt[i][j0] = acc;

      float4 sz = *(const float4*)&sig[i][j0];
      for (int k = 0; k < 16; ++k) {
        float a = Ks[i][k];
        float4 c4 = *(const float4*)&cts[k][j0];
        sz.x = fmaf(-a, c4.x, sz.x); sz.y = fmaf(-a, c4.y, sz.y);
        sz.z = fmaf(-a, c4.z, sz.z); sz.w = fmaf(-a, c4.w, sz.w);
      }
      st4<F32>(out, OFF_SIGF + tb * 1024 + (i * 32 + j0), sz);
    }
    if (tid < 128) {
      int i = tid >> 2, j0 = (tid & 3) << 2;
      float4 acc = make_float4(0.f, 0.f, 0.f, 0.f);
      for (int k = 0; k < 32; ++k) {
        float a = an[i][k];
        float4 k4 = *(const float4*)&Ks[k][j0];
        acc.x = fmaf(a, k4.x, acc.x); acc.y = fmaf(a, k4.y, acc.y);
        acc.z = fmaf(a, k4.z, acc.z); acc.w = fmaf(a, k4.w, acc.w);
      }
      *(float4*)&Um[i][j0] = acc;
    } else if (tid < 160) {
      int i = tid - 128;
      float s = muv[i];
      for (int k = 0; k < 16; ++k) s = fmaf(cts[k][i], yv[k], s);
      muz[i] = s;
      st1<F32>(out, OFF_MUF + tb * 32 + i, s);
    }
    __syncthreads();

    {
      int i = tid >> 3, j0 = (tid & 7) << 2;
      float4 acc = *(const float4*)&asAt[i][j0];
      for (int k = 0; k < 16; ++k) {
        float u = Um[i][k];
        float4 v4 = *(const float4*)&Vm[k][j0];
        acc.x = fmaf(-u, v4.x, acc.x); acc.y = fmaf(-u, v4.y, acc.y);
        acc.z = fmaf(-u, v4.z, acc.z); acc.w = fmaf(-u, v4.w, acc.w);
      }
      if (t < 4) {
        float4 da = make_float4(0.f, 0.f, 0.f, 0.f);
        for (int k = 0; k < 32; ++k) {
          float a = dnm[i][k];
          da.x = fmaf(a, dnm[j0][k],     da.x);
          da.y = fmaf(a, dnm[j0 + 1][k], da.y);
          da.z = fmaf(a, dnm[j0 + 2][k], da.z);
          da.w = fmaf(a, dnm[j0 + 3][k], da.w);
        }
        acc.x += 20.0f * da.x; acc.y += 20.0f * da.y;
        acc.z += 20.0f * da.z; acc.w += 20.0f * da.w;
      }
      *(float4*)&sig[i][j0] = acc;
    }
    if (tid < 32) {
      int i = tid;
      float s = 0.0f;
      for (int k = 0; k < 32; ++k) s = fmaf(an[i][k], muz[k], s);
      const float* chr = ch[t >> 2];
      for (int k = 0; k < 32; ++k) s = fmaf(dnm[i][k], chr[k], s);
      muv[i] = s;
    }
    __syncthreads();
  }
}

// ====================================================================
// fp32 path via MFMA, 3-way bf16 splits (R4 structure, surgically tuned):
//  - rcpf pivots in GJ (kills IEEE-divide sequences)
//  - DPP adds replace shfl_xor in rv / mu_z / mu_next
//  - trunc-based split3; 3-chain MFMA products (dep depth 2)
//  - readlane in prologue chain
// ====================================================================
typedef __attribute__((ext_vector_type(8))) short bf16x8;
typedef __attribute__((ext_vector_type(4))) float f32x4;

#define MFMA16(a, b, c) __builtin_amdgcn_mfma_f32_16x16x32_bf16((a), (b), (c), 0, 0, 0)

__global__ void __launch_bounds__(256)
hkv_f32(const void* __restrict__ obs, const void* __restrict__ A,
        const void* __restrict__ C, const void* __restrict__ D,
        void* __restrict__ out)
{
  if (!data_is_f32(A)) return;
  const int tid = threadIdx.x;
  float* outf = (float*)out;

  if (blockIdx.x >= BB) {
    const int fb = blockIdx.x - BB;
    const int NG = (TT * BB * 2 * 32 * 32) / 4;
    for (int g = fb * 256 + tid; g < NG; g += BB * 256) {
      int e0 = g << 2;
      int R  = e0 >> 5;
      int c0 = e0 & 31;
      int zi = R & 31;
      int l  = (R >> 5) & 1;
      int t  = R >> 13;
      float dv = 0.0f;
      if (l == 0) { if (t >= 2) dv = 0.08f; }
      else        { if (t < 4)  dv = 20.0f; }
      float4 w = make_float4(0.f, 0.f, 0.f, 0.f);
      if (dv != 0.0f && zi >= c0 && zi < c0 + 4) ((float*)&w)[zi - c0] = dv;
      st4<1>(out, OFF_LV + (long)e0, w);
    }
    return;
  }

  const int b    = blockIdx.x;
  const int lane = tid & 63;
  const int wv   = tid >> 6;          // wave 0..3
  const int tm   = wv >> 1;           // quadrant row block
  const int tn   = wv & 1;            // quadrant col block
  const int lr   = lane & 15;
  const int lk   = lane >> 4;
  const int lk8  = lk << 3;
  const int pi   = tid >> 3;          // input-slice row (0..31)
  const int pj   = (tid & 7) << 2;    // input-slice col base

  const float* Of = (const float*)obs;

  // 3-way split planes. Strides 40/24 ushorts (80/48 B, 16B multiples).
  __shared__ __align__(16) ushort sg[3][32][40];   // sigma
  __shared__ __align__(16) ushort an[3][32][40];   // A[:,t+1,0]
  __shared__ __align__(16) ushort dn[3][32][40];   // D[:,t+1,0]
  __shared__ __align__(16) ushort as_[3][32][40];  // An*sigma
  __shared__ __align__(16) ushort ct[3][16][40];   // C_t
  __shared__ __align__(16) ushort wt[3][16][40];   // W^T = C*sigma
  __shared__ __align__(16) ushort kt[3][16][40];   // K^T
  __shared__ __align__(16) ushort w_[3][32][24];   // W = sigma*C^T
  __shared__ __align__(16) ushort ks[3][32][24];   // K
  __shared__ __align__(16) ushort u_[3][32][24];   // U = An*K
  __shared__ __align__(16) ushort aw[3][32][24];   // AW = An*W
  __shared__ __align__(16) float Ssf[16][20];
  __shared__ __align__(16) float wtf[16][36];      // fp32 mirror of W^T
  __shared__ __align__(16) float ch[24][32];
  __shared__ __align__(16) float muv[32];
  __shared__ __align__(16) float muzv[32];
  __shared__ __align__(16) float rv[16];
  __shared__ __align__(16) float yv[16];
  __shared__ __align__(16) float ov[16];

  const bf16x8 z8 = {0, 0, 0, 0, 0, 0, 0, 0};
  #define F40(arr, rb) (*(const bf16x8*)&(arr)[(rb) + lr][lk8])
  #define F24(arr, rb) ((lk < 2) ? (*(const bf16x8*)&(arr)[(rb) + lr][lk8]) : z8)
  // full-precision product; 3 independent accumulator chains (dep depth 2)
  #define PROD_F(acc, X, xb, Y, yb) do { \
    bf16x8 xh_=F40(X[0],(xb)), xm_=F40(X[1],(xb)), xl_=F40(X[2],(xb)); \
    bf16x8 yh_=F40(Y[0],(yb)), ym_=F40(Y[1],(yb)), yl_=F40(Y[2],(yb)); \
    f32x4 a1_ = {0.f,0.f,0.f,0.f}; f32x4 a2_ = {0.f,0.f,0.f,0.f}; \
    acc=MFMA16(xh_,yh_,acc); a1_=MFMA16(xm_,yh_,a1_); a2_=MFMA16(xh_,ym_,a2_); \
    acc=MFMA16(xl_,yh_,acc); a1_=MFMA16(xm_,ym_,a1_); a2_=MFMA16(xh_,yl_,a2_); \
    acc += a1_ + a2_; } while(0)
  #define PROD_H(acc, X, xb, Y, yb) do { \
    bf16x8 xh_=F24(X[0],(xb)), xm_=F24(X[1],(xb)), xl_=F24(X[2],(xb)); \
    bf16x8 yh_=F24(Y[0],(yb)), ym_=F24(Y[1],(yb)), yl_=F24(Y[2],(yb)); \
    f32x4 a1_ = {0.f,0.f,0.f,0.f}; f32x4 a2_ = {0.f,0.f,0.f,0.f}; \
    acc=MFMA16(xh_,yh_,acc); a1_=MFMA16(xm_,yh_,a1_); a2_=MFMA16(xh_,ym_,a2_); \
    acc=MFMA16(xl_,yh_,acc); a1_=MFMA16(xm_,ym_,a1_); a2_=MFMA16(xh_,yl_,a2_); \
    acc += a1_ + a2_; } while(0)
  #define SPLW(ARR, rr, cc, x) do { ushort h_,m_,l_; split3((x),h_,m_,l_); \
    ARR[0][rr][cc]=h_; ARR[1][rr][cc]=m_; ARR[2][rr][cc]=l_; } while(0)

  // ---------------- prologue ----------------
  float anc[4], dnc[4], ccur[4] = {0.f,0.f,0.f,0.f};
  {
    float4 a4 = ld4<1>(A, ((long)(b * TT + 1) * 3) * 1024 + (tid << 2));
    float4 d4 = ld4<1>(D, ((long)(b * TT + 1) * 2) * 1024 + (tid << 2));
    anc[0]=a4.x; anc[1]=a4.y; anc[2]=a4.z; anc[3]=a4.w;
    dnc[0]=d4.x; dnc[1]=d4.y; dnc[2]=d4.z; dnc[3]=d4.w;
    #pragma unroll
    for (int u = 0; u < 4; ++u) { SPLW(an, pi, pj+u, anc[u]); SPLW(dn, pi, pj+u, dnc[u]); }
  }
  if (tid < 128) {
    float4 c4 = ld4<1>(C, ((long)b * TT) * 512 + (tid << 2));
    ccur[0]=c4.x; ccur[1]=c4.y; ccur[2]=c4.z; ccur[3]=c4.w;
    #pragma unroll
    for (int u = 0; u < 4; ++u) SPLW(ct, tid >> 3, ((tid & 7) << 2) + u, ccur[u]);
  } else if (tid < 144) {
    ov[tid - 128] = Of[(long)b * 16 + (tid - 128)];
  }
  for (int idx = tid; idx < 1024; idx += 256) {
    int i = idx >> 5, j = idx & 31;
    sg[0][i][j] = (i == j) ? 0x41A0 : 0;   // bf16(20.0), exact
    sg[1][i][j] = 0; sg[2][i][j] = 0;
  }
  if (tid < 32) muv[tid] = 0.0f;

  float sig_reg[4];                           // exact fp32 sigma quadrant elems
  #pragma unroll
  for (int v = 0; v < 4; ++v) {
    int rr = 16 * tm + lk * 4 + v, cc = 16 * tn + lr;
    sig_reg[v] = (rr == cc) ? 20.0f : 0.0f;
  }

  if (tid < 32) {   // level-1 jump-mean chain (fp32; readlane broadcasts)
    const int zi = tid;
    float m = 0.01f;
    ch[0][zi] = m;
    float curv[32], nxtv[32];
    {
      long base = (((long)b * TT + 4) * 3 + 2) * 1024 + zi * 32;
      #pragma unroll
      for (int u = 0; u < 8; ++u) {
        float4 v = ld4<1>(A, base + u * 4);
        nxtv[4*u]=v.x; nxtv[4*u+1]=v.y; nxtv[4*u+2]=v.z; nxtv[4*u+3]=v.w;
      }
    }
    for (int j = 1; j < 24; ++j) {
      #pragma unroll
      for (int u = 0; u < 32; ++u) curv[u] = nxtv[u];
      if (j < 23) {
        long base = (((long)b * TT + 4 * (j + 1)) * 3 + 2) * 1024 + zi * 32;
        #pragma unroll
        for (int u = 0; u < 8; ++u) {
          float4 v = ld4<1>(A, base + u * 4);
          nxtv[4*u]=v.x; nxtv[4*u+1]=v.y; nxtv[4*u+2]=v.z; nxtv[4*u+3]=v.w;
        }
      }
      float mp = m, s = 0.0f;
      #pragma unroll
      for (int k = 0; k < 32; ++k) s = fmaf(curv[k], readlane_f(mp, k), s);
      m = s;
      ch[j][zi] = m;
    }
  }
  BAR();

  for (int t = 0; t < TT; ++t) {
    const long tb = (long)t * BB + b;

    // ===== P1: sigma_pred out + asig (all); W (w2,w3); rv (w0,w1, reg-based);
    //           LM+MUP (w1 tail) =====
    {
      f32x4 acc = {0.f, 0.f, 0.f, 0.f};
      PROD_F(acc, an, 16 * tm, sg, 16 * tn);      // B = sigma (symmetric)
      #pragma unroll
      for (int v = 0; v < 4; ++v) {
        int rr = 16 * tm + lk * 4 + v, cc = 16 * tn + lr;
        outf[OFF_SIGP + tb * 1024 + rr * 32 + cc] = sig_reg[v];
        SPLW(as_, rr, cc, acc[v]);
      }
    }
    if (wv >= 2) {
      const int a = wv - 2;
      f32x4 acc = {0.f, 0.f, 0.f, 0.f};
      PROD_F(acc, sg, 16 * a, ct, 0);             // W = sigma*C^T  (B^T = C)
      #pragma unroll
      for (int v = 0; v < 4; ++v) {
        int row = 16 * a + lk * 4 + v;
        ushort h_, m_, l_; split3(acc[v], h_, m_, l_);
        w_[0][row][lr]=h_; w_[1][row][lr]=m_; w_[2][row][lr]=l_;
        wt[0][lr][row]=h_; wt[1][lr][row]=m_; wt[2][lr][row]=l_;
        wtf[lr][row] = acc[v];                    // fp32 mirror for the solve
      }
    } else {
      // rv[i] = ov[i] - C[i,:]*mu ; register-resident C, 8 lanes/row, DPP tree
      float4 m4 = *(const float4*)&muv[pj];
      float part = ccur[0] * m4.x;
      part = fmaf(ccur[1], m4.y, part);
      part = fmaf(ccur[2], m4.z, part);
      part = fmaf(ccur[3], m4.w, part);
      part = dpp_addf<0xB1>(part);
      part = dpp_addf<0x4E>(part);
      part = dpp_addf<0x141>(part);
      if ((tid & 7) == 0) rv[pi] = ov[pi] - part;
      if (wv == 1) {  // latent_means + mu_pred
        int l = lane >> 5, zi = lane & 31;
        outf[OFF_LM + (tb * 2 + l) * 32 + zi] = l ? ch[t >> 2][zi] : 0.0f;
        if (lane < 32) outf[OFF_MUP + tb * 32 + zi] = muv[zi];
      }
    }
    BAR();

    // ===== P2: prefetch-issue; asAt + Dterm (all); S+GJ (w0); AW (w1,w2)
    float pa[4], pd[4], pc[4] = {0.f,0.f,0.f,0.f}; float pobs = 0.f;
    if (t < TT - 1) {
      if (t < TT - 2) {
        float4 a4 = ld4<1>(A, ((long)(b * TT + t + 2) * 3) * 1024 + (tid << 2));
        float4 d4 = ld4<1>(D, ((long)(b * TT + t + 2) * 2) * 1024 + (tid << 2));
        pa[0]=a4.x; pa[1]=a4.y; pa[2]=a4.z; pa[3]=a4.w;
        pd[0]=d4.x; pd[1]=d4.y; pd[2]=d4.z; pd[3]=d4.w;
      } else {                                   // t+1 == TT-1: An=I, Dn=0
        #pragma unroll
        for (int u = 0; u < 4; ++u) { pa[u] = (pi == pj + u) ? 1.0f : 0.0f; pd[u] = 0.0f; }
      }
      if (tid < 128) {
        float4 c4 = ld4<1>(C, ((long)b * TT + (t + 1)) * 512 + (tid << 2));
        pc[0]=c4.x; pc[1]=c4.y; pc[2]=c4.z; pc[3]=c4.w;
      } else if (tid < 144) {
        pobs = Of[((long)(t + 1) * BB + b) * 16 + (tid - 128)];
      }
    }

    f32x4 acc_at = {0.f, 0.f, 0.f, 0.f};
    PROD_F(acc_at, as_, 16 * tm, an, 16 * tn);    // asAt = asig*An^T (B^T = An)
    f32x4 acc_d = {0.f, 0.f, 0.f, 0.f};
    if (t < 4) PROD_F(acc_d, dn, 16 * tm, dn, 16 * tn);  // Dn*Dn^T

    if (wv == 0) {
      f32x4 s4 = {0.f, 0.f, 0.f, 0.f};
      PROD_F(s4, wt, 0, ct, 0);                   // S = W^T * C^T  (B^T = C)
      #pragma unroll
      for (int v = 0; v < 4; ++v) {
        int r = lk * 4 + v;
        float val = s4[v] + ((r == lr) ? 0.03f : 0.0f);
        Ssf[r][lr] = val;
        outf[OFF_ST + tb * 256 + r * 16 + lr] = val;
      }
      // ---- column-per-lane Gauss-Jordan on [S | W^T | r], readlane + rcpf ----
      const int c = lane;
      float gv[16];
      if (c < 16) {
        #pragma unroll
        for (int r = 0; r < 16; ++r) gv[r] = Ssf[r][c];
      } else if (c < 48) {
        #pragma unroll
        for (int r = 0; r < 16; ++r) gv[r] = wtf[r][c - 16];
      } else if (c == 48) {
        #pragma unroll
        for (int r = 0; r < 16; ++r) gv[r] = rv[r];
      } else {
        #pragma unroll
        for (int r = 0; r < 16; ++r) gv[r] = 0.0f;
      }
      #pragma unroll
      for (int p = 0; p < 16; ++p) {
        float f[16];
        #pragma unroll
        for (int r = 0; r < 16; ++r) f[r] = readlane_f(gv[r], p);  // column p
        float rc = __builtin_amdgcn_rcpf(f[p]);   // ~1ulp; S is SPD, safe
        float srow = gv[p] * rc;
        #pragma unroll
        for (int r = 0; r < 16; ++r)
          if (r != p) gv[r] = fmaf(-f[r], srow, gv[r]);
        gv[p] = srow;
      }
      // writeback: lane 16+z holds K row z (K = W S^-1); lane 48 holds y
      if (c >= 16 && c < 48) {
        const int z = c - 16;
        #pragma unroll
        for (int u = 0; u < 8; ++u) {
          ushort h0,m0,l0,h1,m1,l1;
          split3(gv[2*u],   h0, m0, l0);
          split3(gv[2*u+1], h1, m1, l1);
          ((uint*)&ks[0][z][0])[u] = (uint)h0 | ((uint)h1 << 16);
          ((uint*)&ks[1][z][0])[u] = (uint)m0 | ((uint)m1 << 16);
          ((uint*)&ks[2][z][0])[u] = (uint)l0 | ((uint)l1 << 16);
          kt[0][2*u][z] = h0; kt[0][2*u+1][z] = h1;
          kt[1][2*u][z] = m0; kt[1][2*u+1][z] = m1;
          kt[2][2*u][z] = l0; kt[2][2*u+1][z] = l1;
        }
      } else if (c == 48) {
        #pragma unroll
        for (int r = 0; r < 16; ++r) yv[r] = gv[r];
      }
    } else if (wv < 3) {
      const int a = wv - 1;
      f32x4 w4 = {0.f, 0.f, 0.f, 0.f};
      PROD_F(w4, an, 16 * a, wt, 0);              // AW = An*W (B^T = W^T)
      #pragma unroll
      for (int v = 0; v < 4; ++v) SPLW(aw, 16 * a + lk * 4 + v, lr, w4[v]);
    }
    BAR();

    // ===== P3: KW + sigma_filt out (all); U (w2,w3); mu_z + mu_filt (w1)
    {
      f32x4 kw = {0.f, 0.f, 0.f, 0.f};
      PROD_H(kw, ks, 16 * tm, w_, 16 * tn);       // K*W^T (B^T = W), k=16
      #pragma unroll
      for (int v = 0; v < 4; ++v) {
        int rr = 16 * tm + lk * 4 + v, cc = 16 * tn + lr;
        outf[OFF_SIGF + tb * 1024 + rr * 32 + cc] = sig_reg[v] - kw[v];
      }
    }
    if (wv >= 2) {
      const int a = wv - 2;
      f32x4 u4 = {0.f, 0.f, 0.f, 0.f};
      PROD_F(u4, an, 16 * a, kt, 0);              // U = An*K (B^T = K^T), k=32
      #pragma unroll
      for (int v = 0; v < 4; ++v) SPLW(u_, 16 * a + lk * 4 + v, lr, u4[v]);
    } else if (wv == 1) {
      // mu_z[i] = mu[i] + sum_{k<16} W[i,k] y[k] ; W[i,k] = wtf[k][i] (fp32)
      int i = lane >> 1, kg = lane & 1;
      float s = 0.0f;
      #pragma unroll
      for (int u = 0; u < 8; ++u) {
        int k = kg * 8 + u;
        s = fmaf(wtf[k][i], yv[k], s);
      }
      s = dpp_addf<0xB1>(s);                      // pair (2i, 2i+1)
      if (kg == 0) {
        float m = muv[i] + s;
        muzv[i] = m;
        outf[OFF_MUF + tb * 32 + i] = m;
      }
    }
    BAR();

    // ===== P4: sigma' (all); mu_next (all, DPP tree); stage t+1 inputs
    {
      f32x4 uw = {0.f, 0.f, 0.f, 0.f};
      PROD_H(uw, u_, 16 * tm, aw, 16 * tn);       // U*AW^T (B^T = AW), k=16
      #pragma unroll
      for (int v = 0; v < 4; ++v) {
        int rr = 16 * tm + lk * 4 + v, cc = 16 * tn + lr;
        float sp = acc_at[v] - uw[v];
        if (rr == cc) sp += 0.08f;
        if (t < 4) sp = fmaf(20.0f, acc_d[v], sp);
        sig_reg[v] = sp;
        SPLW(sg, rr, cc, sp);
      }
    }
    {
      // mu_next[i] = An[i,:]*muz + Dn[i,:]*ch ; 8 lanes/row, DPP tree
      const float* chr = ch[t >> 2];
      float4 mz4 = *(const float4*)&muzv[pj];
      float4 ch4 = *(const float4*)&chr[pj];
      float part = anc[0] * mz4.x;
      part = fmaf(anc[1], mz4.y, part);
      part = fmaf(anc[2], mz4.z, part);
      part = fmaf(anc[3], mz4.w, part);
      part = fmaf(dnc[0], ch4.x, part);
      part = fmaf(dnc[1], ch4.y, part);
      part = fmaf(dnc[2], ch4.z, part);
      part = fmaf(dnc[3], ch4.w, part);
      part = dpp_addf<0xB1>(part);
      part = dpp_addf<0x4E>(part);
      part = dpp_addf<0x141>(part);
      if ((tid & 7) == 0) muv[pi] = part;
    }
    if (t < TT - 1) {
      #pragma unroll
      for (int u = 0; u < 4; ++u) {
        SPLW(an, pi, pj + u, pa[u]);
        SPLW(dn, pi, pj + u, pd[u]);
        anc[u] = pa[u]; dnc[u] = pd[u];
      }
      if (tid < 128) {
        #pragma unroll
        for (int u = 0; u < 4; ++u) SPLW(ct, tid >> 3, ((tid & 7) << 2) + u, pc[u]);
        #pragma unroll
        for (int u = 0; u < 4; ++u) ccur[u] = pc[u];
      } else if (tid < 144) {
        ov[tid - 128] = pobs;
      }
    }
    BAR();
  }
  #undef F40
  #undef F24
  #undef PROD_F
  #undef PROD_H
  #undef SPLW
}

extern "C" void kernel_launch(void* const* d_in, const int* in_sizes, int n_in,
                              void* d_out, int out_size, void* d_ws, size_t ws_size,
                              hipStream_t stream) {
  const void* obs = d_in[0];
  const void* A   = d_in[1];
  const void* C   = d_in[2];
  const void* D   = d_in[3];
  (void)in_sizes; (void)n_in; (void)out_size; (void)d_ws; (void)ws_size;

  hkv_kernel<0><<<dim3(2 * BB), dim3(256), 0, stream>>>(obs, A, C, D, d_out);
  hkv_f32<<<dim3(2 * BB), dim3(256), 0, stream>>>(obs, A, C, D, d_out);
}